// Round 3
// baseline (1798.088 us; speedup 1.0000x reference)
//
#include <hip/hip_runtime.h>
#include <hip/hip_fp16.h>
#include <cstdint>
#include <cstddef>

#define EMB    2048
#define MAXF   9216
#define NBATCH 4
#define NSEQ   2048
#define MTOT   (NBATCH*NSEQ)   // 8192

typedef _Float16 f16;
typedef _Float16 half8_t  __attribute__((ext_vector_type(8)));
typedef float    float4_t __attribute__((ext_vector_type(4)));

// ---------------- workspace layout (bytes) ----------------
static const size_t OFF_X16   = 0;
static const size_t OFF_GW16  = 33554432;
static const size_t OFF_UW16  = 71303168;
static const size_t OFF_HID   = 109051904;
static const size_t OFF_DW16  = 0;           // overlays x16/gw16 after fused pass
static const size_t OFF_SMALL = 260046848;

// ---------------- small kernels ----------------
__global__ void k_zero(float* __restrict__ p, int n) {
    int i = blockIdx.x * blockDim.x + threadIdx.x;
    if (i < n) p[i] = 0.f;
}

__global__ void k_cast_f2h(const float* __restrict__ s, f16* __restrict__ d, int n8) {
    int i   = blockIdx.x * blockDim.x + threadIdx.x;
    int str = gridDim.x * blockDim.x;
    for (; i < n8; i += str) {
        const float4* p = (const float4*)(s + (size_t)i * 8);
        float4 a = p[0], b = p[1];
        half8_t h;
        h[0] = (f16)a.x; h[1] = (f16)a.y; h[2] = (f16)a.z; h[3] = (f16)a.w;
        h[4] = (f16)b.x; h[5] = (f16)b.y; h[6] = (f16)b.z; h[7] = (f16)b.w;
        *(half8_t*)(d + (size_t)i * 8) = h;
    }
}

__global__ void k_meanpart(const float* __restrict__ x, float* __restrict__ meanx) {
    int bid = blockIdx.x;            // 256 blocks: b(4) x sc(8) x ec(8)
    int b  = bid >> 6;
    int sc = (bid >> 3) & 7;
    int ec = bid & 7;
    int e  = (ec << 8) + threadIdx.x;
    const float* p = x + (size_t)b * NSEQ * EMB + (size_t)(sc * 256) * EMB + e;
    float acc = 0.f;
    #pragma unroll 4
    for (int s2 = 0; s2 < 256; ++s2) acc += p[(size_t)s2 * EMB];
    atomicAdd(&meanx[b * EMB + e], acc);
}

__global__ void k_pred1(const float* __restrict__ meanx, const float* __restrict__ w1,
                        float* __restrict__ hbuf) {
    int g    = blockIdx.x * 4 + (threadIdx.x >> 6);  // 2048 waves
    int lane = threadIdx.x & 63;
    int b = g >> 9, j = g & 511;
    const float* mp = meanx + b * EMB;
    const float* wp = w1 + (size_t)j * EMB;
    float acc = 0.f;
    #pragma unroll 8
    for (int t = 0; t < 32; ++t) { int e = (t << 6) + lane; acc += mp[e] * wp[e]; }
    for (int o = 1; o < 64; o <<= 1) acc += __shfl_xor(acc, o);
    if (lane == 0) {
        float v = acc * (1.0f / (float)NSEQ);
        hbuf[(b << 9) + j] = v / (1.f + expf(-v));
    }
}

__global__ void k_pred2(const float* __restrict__ hbuf, const float* __restrict__ w2,
                        float* __restrict__ scal_f, int* __restrict__ scal_i) {
    int lane = threadIdx.x & 63;
    float rs = 0.f;
    for (int b = 0; b < 4; ++b) {
        float a = 0.f;
        #pragma unroll
        for (int t = 0; t < 8; ++t) { int e = (t << 6) + lane; a += hbuf[(b << 9) + e] * w2[e]; }
        for (int o = 1; o < 64; o <<= 1) a += __shfl_xor(a, o);
        float r = 1.f / (1.f + expf(-a));
        float ratio = 1.0f + (r - 0.5f);            // *2*ADAPT with ADAPT=0.5
        ratio = fminf(fmaxf(ratio, 0.5f), 1.5f);
        rs += ratio;
    }
    float n = floorf(6144.0f * (rs * 0.25f));
    n = fminf(fmaxf(n, 1.0f), 9216.0f);
    if (threadIdx.x == 0) { scal_f[0] = n; scal_i[0] = (int)n; }
}

// ---------------- staging helper ----------------
__device__ __forceinline__ void gload16(const f16* g, f16* l) {
    __builtin_amdgcn_global_load_lds((const __attribute__((address_space(1))) void*)g,
                                     (__attribute__((address_space(3))) void*)l, 16, 0, 0);
}

// ---------------- fused gate+up GEMM: 128x64 tile, BK=64, 4 waves, 2-phase dbuf ----
// LDS buffer layout (halves): [0,8192)=A [k8(8)][row(128)][8], [8192,12288)=Bg, [12288,16384)=Bu
__global__ __launch_bounds__(256, 2) void k_gemm_fused(const f16* __restrict__ x16,
                                                       const f16* __restrict__ gw16,
                                                       const f16* __restrict__ uw16,
                                                       f16* __restrict__ hid16,
                                                       const float* __restrict__ normw,
                                                       float* __restrict__ sumsq,
                                                       const int* __restrict__ np) {
    __shared__ __align__(16) f16 S[2][16384];
    const int nint = *np;
    const int ncol0 = blockIdx.y << 6;          // mrow fast-varying for L2 locality
    if (ncol0 >= nint) return;
    const int mrow0 = blockIdx.x << 7;
    const int wave = threadIdx.x >> 6, lane = threadIdx.x & 63;
    const int wr = wave >> 1, wc = wave & 1;    // 2M x 2N -> per-wave 64x32 per matrix
    const int q = lane >> 4, r = lane & 15;

    float4_t acc_g[4][2], acc_u[4][2];
    const float4_t z = {0.f, 0.f, 0.f, 0.f};
    #pragma unroll
    for (int m = 0; m < 4; ++m)
        #pragma unroll
        for (int nn = 0; nn < 2; ++nn) { acc_g[m][nn] = z; acc_u[m][nn] = z; }

    auto STAGE = [&](int buf, int kt) {
        const int k0 = kt << 6;
        #pragma unroll
        for (int t = 0; t < 8; ++t) {
            f16* dst = &S[buf][(size_t)(((wave << 3) + t) << 9)];
            if (wave < 2) {
                int i = (wave << 9) + (t << 6) + lane;          // [0,1024)
                gload16(x16 + (size_t)(mrow0 + (i & 127)) * EMB + k0 + ((i >> 7) << 3), dst);
            } else if (wave == 2) {
                int j = (t << 6) + lane;                        // [0,512)
                gload16(gw16 + (size_t)(ncol0 + (j & 63)) * EMB + k0 + ((j >> 6) << 3), dst);
            } else {
                int j = (t << 6) + lane;
                gload16(uw16 + (size_t)(ncol0 + (j & 63)) * EMB + k0 + ((j >> 6) << 3), dst);
            }
        }
    };

    auto COMPUTE = [&](int buf) {
        const f16* Sc = &S[buf][0];
        #pragma unroll
        for (int ks = 0; ks < 2; ++ks) {
            const int kq = (ks << 2) + q;
            half8_t af[4], bg[2], bu[2];
            #pragma unroll
            for (int m = 0; m < 4; ++m)
                af[m] = *(const half8_t*)(Sc + ((kq << 7) + (wr << 6) + (m << 4) + r) * 8);
            #pragma unroll
            for (int nn = 0; nn < 2; ++nn) {
                int brow = ((kq << 6) + (wc << 5) + (nn << 4) + r) * 8;
                bg[nn] = *(const half8_t*)(Sc + 8192 + brow);
                bu[nn] = *(const half8_t*)(Sc + 12288 + brow);
            }
            #pragma unroll
            for (int m = 0; m < 4; ++m)
                #pragma unroll
                for (int nn = 0; nn < 2; ++nn) {
                    acc_g[m][nn] = __builtin_amdgcn_mfma_f32_16x16x32_f16(af[m], bg[nn], acc_g[m][nn], 0, 0, 0);
                    acc_u[m][nn] = __builtin_amdgcn_mfma_f32_16x16x32_f16(af[m], bu[nn], acc_u[m][nn], 0, 0, 0);
                }
        }
    };

    // 2-phase pipeline over 32 K-tiles
    STAGE(0, 0);
    __syncthreads();
    int cur = 0;
    for (int kt = 0; kt < 31; ++kt) {
        STAGE(cur ^ 1, kt + 1);     // loads fly during compute below
        COMPUTE(cur);
        __syncthreads();            // drains vmcnt(0): next buffer ready, this one free
        cur ^= 1;
    }
    COMPUTE(cur);

    // epilogue: h = silu(g)*u (masked), ssq per row, store h*norm_w as fp16
    #pragma unroll
    for (int m = 0; m < 4; ++m)
        #pragma unroll
        for (int j = 0; j < 4; ++j) {
            int grow = mrow0 + (wr << 6) + (m << 4) + (q << 2) + j;
            float ssq = 0.f;
            #pragma unroll
            for (int nn = 0; nn < 2; ++nn) {
                int col = ncol0 + (wc << 5) + (nn << 4) + r;
                float v = 0.f;
                if (col < nint) {
                    float g = acc_g[m][nn][j];
                    float sg = g / (1.f + expf(-g));
                    v = sg * acc_u[m][nn][j];
                    ssq += v * v;
                    v *= normw[col];
                }
                hid16[(size_t)grow * MAXF + col] = (f16)v;
            }
            ssq += __shfl_xor(ssq, 1);
            ssq += __shfl_xor(ssq, 2);
            ssq += __shfl_xor(ssq, 4);
            ssq += __shfl_xor(ssq, 8);
            if (r == 0) atomicAdd(&sumsq[grow], ssq);
        }
}

// ---------------- down GEMM: 128x128 tile, BK=64, 4 waves, 2-phase dbuf ----------------
// LDS buffer layout (halves): [0,8192)=A, [8192,16384)=B
__global__ __launch_bounds__(256, 2) void k_gemm_down(const f16* __restrict__ hid16,
                                                      const f16* __restrict__ dw16,
                                                      float* __restrict__ out,
                                                      const float* __restrict__ sumsq,
                                                      const float* __restrict__ nfp,
                                                      const int* __restrict__ np) {
    __shared__ __align__(16) f16 S[2][16384];
    const int nint = *np;
    const float nf = *nfp;
    const int kT = (nint + 63) >> 6;
    const int ncol0 = blockIdx.y << 7;          // e dimension (2048 -> 16 y-blocks)
    const int mrow0 = blockIdx.x << 7;
    const int wave = threadIdx.x >> 6, lane = threadIdx.x & 63;
    const int wr = wave >> 1, wc = wave & 1;
    const int q = lane >> 4, r = lane & 15;

    float4_t acc[4][4];
    const float4_t z = {0.f, 0.f, 0.f, 0.f};
    #pragma unroll
    for (int m = 0; m < 4; ++m)
        #pragma unroll
        for (int nn = 0; nn < 4; ++nn) acc[m][nn] = z;

    auto STAGE = [&](int buf, int kt) {
        const int k0 = kt << 6;
        #pragma unroll
        for (int t = 0; t < 8; ++t) {
            f16* dst = &S[buf][(size_t)(((wave << 3) + t) << 9)];
            int i = ((wave & 1) << 9) + (t << 6) + lane;        // [0,1024) within region
            int row = i & 127, k8 = i >> 7;
            if (wave < 2) gload16(hid16 + (size_t)(mrow0 + row) * MAXF + k0 + (k8 << 3), dst);
            else          gload16(dw16  + (size_t)(ncol0 + row) * MAXF + k0 + (k8 << 3), dst);
        }
    };

    auto COMPUTE = [&](int buf) {
        const f16* Sc = &S[buf][0];
        #pragma unroll
        for (int ks = 0; ks < 2; ++ks) {
            const int kq = (ks << 2) + q;
            half8_t af[4], bf[4];
            #pragma unroll
            for (int m = 0; m < 4; ++m)
                af[m] = *(const half8_t*)(Sc + ((kq << 7) + (wr << 6) + (m << 4) + r) * 8);
            #pragma unroll
            for (int nn = 0; nn < 4; ++nn)
                bf[nn] = *(const half8_t*)(Sc + 8192 + ((kq << 7) + (wc << 6) + (nn << 4) + r) * 8);
            #pragma unroll
            for (int m = 0; m < 4; ++m)
                #pragma unroll
                for (int nn = 0; nn < 4; ++nn)
                    acc[m][nn] = __builtin_amdgcn_mfma_f32_16x16x32_f16(af[m], bf[nn], acc[m][nn], 0, 0, 0);
        }
    };

    STAGE(0, 0);
    __syncthreads();
    int cur = 0;
    for (int kt = 0; kt < kT - 1; ++kt) {
        STAGE(cur ^ 1, kt + 1);
        COMPUTE(cur);
        __syncthreads();
        cur ^= 1;
    }
    COMPUTE(cur);

    #pragma unroll
    for (int m = 0; m < 4; ++m)
        #pragma unroll
        for (int j = 0; j < 4; ++j) {
            int grow = mrow0 + (wr << 6) + (m << 4) + (q << 2) + j;
            float rms = sqrtf(sumsq[grow] / nf + 1e-6f);
            rms = fminf(fmaxf(rms, 1e-6f), 1e6f);
            float inv = 1.f / rms;
            #pragma unroll
            for (int nn = 0; nn < 4; ++nn) {
                int col = ncol0 + (wc << 6) + (nn << 4) + r;
                out[(size_t)grow * EMB + col] = acc[m][nn][j] * inv;
            }
        }
}

// ---------------- launch ----------------
extern "C" void kernel_launch(void* const* d_in, const int* in_sizes, int n_in,
                              void* d_out, int out_size, void* d_ws, size_t ws_size,
                              hipStream_t stream) {
    (void)in_sizes; (void)n_in; (void)out_size; (void)ws_size;
    const float* x  = (const float*)d_in[0];
    const float* w1 = (const float*)d_in[1];
    const float* w2 = (const float*)d_in[2];
    const float* gw = (const float*)d_in[3];
    const float* uw = (const float*)d_in[4];
    const float* dw = (const float*)d_in[5];
    const float* nw = (const float*)d_in[6];
    float* out = (float*)d_out;
    char* ws = (char*)d_ws;

    f16* x16   = (f16*)(ws + OFF_X16);
    f16* gw16  = (f16*)(ws + OFF_GW16);
    f16* uw16  = (f16*)(ws + OFF_UW16);
    f16* hid16 = (f16*)(ws + OFF_HID);
    f16* dw16  = (f16*)(ws + OFF_DW16);
    float* sumsq  = (float*)(ws + OFF_SMALL);
    float* meanx  = (float*)(ws + OFF_SMALL + 32768);
    float* hbuf   = (float*)(ws + OFF_SMALL + 65536);
    float* scal_f = (float*)(ws + OFF_SMALL + 73728);
    int*   scal_i = (int*)(ws + OFF_SMALL + 73728 + 4);

    // zero accumulators (sumsq + meanx contiguous: 16384 floats)
    k_zero<<<64, 256, 0, stream>>>(sumsq, 16384);

    // fp32 -> fp16 conversions
    k_cast_f2h<<<1024, 256, 0, stream>>>(x,  x16,  (MTOT * EMB) / 8);
    k_cast_f2h<<<1024, 256, 0, stream>>>(gw, gw16, (MAXF * EMB) / 8);
    k_cast_f2h<<<1024, 256, 0, stream>>>(uw, uw16, (MAXF * EMB) / 8);

    // dim predictor (fp32, exact-path)
    k_meanpart<<<256, 256, 0, stream>>>(x, meanx);
    k_pred1<<<512, 256, 0, stream>>>(meanx, w1, hbuf);
    k_pred2<<<1, 64, 0, stream>>>(hbuf, w2, scal_f, scal_i);

    // fused gate+up SwiGLU  (mrow = blockIdx.x fast-varying)
    k_gemm_fused<<<dim3(64, 144), 256, 0, stream>>>(x16, gw16, uw16, hid16, nw, sumsq, scal_i);

    // down projection
    k_cast_f2h<<<1024, 256, 0, stream>>>(dw, dw16, (EMB * MAXF) / 8);   // overlays dead x16/gw16
    k_gemm_down<<<dim3(64, 16), 256, 0, stream>>>(hid16, dw16, out, sumsq, scal_f, scal_i);
}

// Round 5
// 1601.148 us; speedup vs baseline: 1.1230x; 1.1230x over previous
//
#include <hip/hip_runtime.h>
#include <hip/hip_fp16.h>
#include <cstdint>
#include <cstddef>

#define EMB    2048
#define MAXF   9216
#define NBATCH 4
#define NSEQ   2048
#define MTOT   (NBATCH*NSEQ)   // 8192

typedef _Float16 f16;
typedef _Float16 half8_t  __attribute__((ext_vector_type(8)));
typedef float    float4_t __attribute__((ext_vector_type(4)));

#define BARRIER()  __builtin_amdgcn_s_barrier()
#define VMCNT6()   asm volatile("s_waitcnt vmcnt(6)" ::: "memory")
#define VMCNT0()   asm volatile("s_waitcnt vmcnt(0)" ::: "memory")
#define LGKM0()    do { asm volatile("s_waitcnt lgkmcnt(0)" ::: "memory"); \
                        __builtin_amdgcn_sched_barrier(0); } while (0)

// ---------------- workspace layout (bytes) ----------------
static const size_t OFF_X16   = 0;
static const size_t OFF_GW16  = 33554432;
static const size_t OFF_UW16  = 71303168;
static const size_t OFF_HID   = 109051904;
static const size_t OFF_DW16  = 0;           // overlays x16/gw16 after fused pass
static const size_t OFF_SMALL = 260046848;

// ---------------- small kernels ----------------
__global__ void k_zero(float* __restrict__ p, int n) {
    int i = blockIdx.x * blockDim.x + threadIdx.x;
    if (i < n) p[i] = 0.f;
}

__global__ void k_cast_f2h(const float* __restrict__ s, f16* __restrict__ d, int n8) {
    int i   = blockIdx.x * blockDim.x + threadIdx.x;
    int str = gridDim.x * blockDim.x;
    for (; i < n8; i += str) {
        const float4* p = (const float4*)(s + (size_t)i * 8);
        float4 a = p[0], b = p[1];
        half8_t h;
        h[0] = (f16)a.x; h[1] = (f16)a.y; h[2] = (f16)a.z; h[3] = (f16)a.w;
        h[4] = (f16)b.x; h[5] = (f16)b.y; h[6] = (f16)b.z; h[7] = (f16)b.w;
        *(half8_t*)(d + (size_t)i * 8) = h;
    }
}

__global__ void k_meanpart(const float* __restrict__ x, float* __restrict__ meanx) {
    int bid = blockIdx.x;            // 256 blocks: b(4) x sc(8) x ec(8)
    int b  = bid >> 6;
    int sc = (bid >> 3) & 7;
    int ec = bid & 7;
    int e  = (ec << 8) + threadIdx.x;
    const float* p = x + (size_t)b * NSEQ * EMB + (size_t)(sc * 256) * EMB + e;
    float acc = 0.f;
    #pragma unroll 4
    for (int s2 = 0; s2 < 256; ++s2) acc += p[(size_t)s2 * EMB];
    atomicAdd(&meanx[b * EMB + e], acc);
}

__global__ void k_pred1(const float* __restrict__ meanx, const float* __restrict__ w1,
                        float* __restrict__ hbuf) {
    int g    = blockIdx.x * 4 + (threadIdx.x >> 6);  // 2048 waves
    int lane = threadIdx.x & 63;
    int b = g >> 9, j = g & 511;
    const float* mp = meanx + b * EMB;
    const float* wp = w1 + (size_t)j * EMB;
    float acc = 0.f;
    #pragma unroll 8
    for (int t = 0; t < 32; ++t) { int e = (t << 6) + lane; acc += mp[e] * wp[e]; }
    for (int o = 1; o < 64; o <<= 1) acc += __shfl_xor(acc, o);
    if (lane == 0) {
        float v = acc * (1.0f / (float)NSEQ);
        hbuf[(b << 9) + j] = v / (1.f + expf(-v));
    }
}

__global__ void k_pred2(const float* __restrict__ hbuf, const float* __restrict__ w2,
                        float* __restrict__ scal_f, int* __restrict__ scal_i) {
    int lane = threadIdx.x & 63;
    float rs = 0.f;
    for (int b = 0; b < 4; ++b) {
        float a = 0.f;
        #pragma unroll
        for (int t = 0; t < 8; ++t) { int e = (t << 6) + lane; a += hbuf[(b << 9) + e] * w2[e]; }
        for (int o = 1; o < 64; o <<= 1) a += __shfl_xor(a, o);
        float r = 1.f / (1.f + expf(-a));
        float ratio = 1.0f + (r - 0.5f);            // *2*ADAPT with ADAPT=0.5
        ratio = fminf(fmaxf(ratio, 0.5f), 1.5f);
        rs += ratio;
    }
    float n = floorf(6144.0f * (rs * 0.25f));
    n = fminf(fmaxf(n, 1.0f), 9216.0f);
    if (threadIdx.x == 0) { scal_f[0] = n; scal_i[0] = (int)n; }
}

// ---------------- staging helper ----------------
__device__ __forceinline__ void gload16(const f16* g, f16* l) {
    __builtin_amdgcn_global_load_lds((const __attribute__((address_space(1))) void*)g,
                                     (__attribute__((address_space(3))) void*)l, 16, 0, 0);
}

// =======================================================================================
// fused gate+up GEMM: BM=256, BN=64, BK=64, 8 waves (2M x 4N), 3-buffer counted-vmcnt
// LDS per buffer (48KB = 24576 halves): slots of 1KB (64 lanes x 16B):
//   A  slots  0..31 : k8 = s>>2, rowblk = s&3 (64 rows each)   [256 rows x 64 k]
//   Bg slots 32..39 : k8 = s-32                                 [64 cols x 64 k]
//   Bu slots 40..47 : k8 = s-40
// =======================================================================================
__global__ __launch_bounds__(512, 2) void k_gemm_fused(const f16* __restrict__ x16,
                                                       const f16* __restrict__ gw16,
                                                       const f16* __restrict__ uw16,
                                                       f16* __restrict__ hid16,
                                                       const float* __restrict__ normw,
                                                       float* __restrict__ sumsq,
                                                       const int* __restrict__ np) {
    __shared__ __align__(16) f16 S[3 * 24576];   // 144 KB
    const int nint = *np;
    const int ncol0 = blockIdx.y << 6;
    if (ncol0 >= nint) return;
    const int mrow0 = blockIdx.x << 8;
    const int wave = threadIdx.x >> 6, lane = threadIdx.x & 63;
    const int wr = wave >> 2, wc = wave & 3;       // per-wave out: 128 rows x 16 cols (per matrix)
    const int q = lane >> 4, r = lane & 15;
    const int KT = EMB / 64;                       // 32

    float4_t acc_g[8], acc_u[8];
    const float4_t z = {0.f, 0.f, 0.f, 0.f};
    #pragma unroll
    for (int m = 0; m < 8; ++m) { acc_g[m] = z; acc_u[m] = z; }

    // issue 3 of this wave's 6 slots for K-tile kt into buffer buf
    auto STAGE3 = [&](int buf, int kt, int half) {
        const int k0 = kt << 6;
        #pragma unroll
        for (int u = 0; u < 3; ++u) {
            const int s = wave * 6 + half * 3 + u;
            f16* dst = &S[buf * 24576 + (s << 9)];
            const f16* src;
            if (s < 32)      { int k8 = s >> 2, rb = s & 3;
                               src = x16  + (size_t)(mrow0 + (rb << 6) + lane) * EMB + k0 + (k8 << 3); }
            else if (s < 40) { int k8 = s - 32;
                               src = gw16 + (size_t)(ncol0 + lane) * EMB + k0 + (k8 << 3); }
            else             { int k8 = s - 40;
                               src = uw16 + (size_t)(ncol0 + lane) * EMB + k0 + (k8 << 3); }
            gload16(src, dst);
        }
    };

    // one phase: ds-load frags (ks), prefetch 3 slots, barrier, lgkm, 16 MFMA, barrier
    auto PHASE = [&](int buf, int ks, int preBuf, int preKt, bool pre) {
        const f16* Sc = &S[buf * 24576];
        const int kq = (ks << 2) + q;
        half8_t af[8], bg, bu;
        #pragma unroll
        for (int m = 0; m < 8; ++m) {
            int row = (wr << 7) + (m << 4) + r;
            af[m] = *(const half8_t*)(Sc + (((kq << 2) + (row >> 6)) << 9) + ((row & 63) << 3));
        }
        {
            int col = (wc << 4) + r;
            bg = *(const half8_t*)(Sc + ((32 + kq) << 9) + (col << 3));
            bu = *(const half8_t*)(Sc + ((40 + kq) << 9) + (col << 3));
        }
        if (pre) STAGE3(preBuf, preKt, ks);
        BARRIER();
        LGKM0();
        __builtin_amdgcn_s_setprio(1);
        #pragma unroll
        for (int m = 0; m < 8; ++m) {
            acc_g[m] = __builtin_amdgcn_mfma_f32_16x16x32_f16(af[m], bg, acc_g[m], 0, 0, 0);
            acc_u[m] = __builtin_amdgcn_mfma_f32_16x16x32_f16(af[m], bu, acc_u[m], 0, 0, 0);
        }
        __builtin_amdgcn_s_setprio(0);
        BARRIER();
    };

    // prologue: stage tiles 0 and 1 (12 loads in flight per thread)
    STAGE3(0, 0, 0); STAGE3(0, 0, 1);
    STAGE3(1, 1, 0); STAGE3(1, 1, 1);

    int b0 = 0;
    for (int kt = 0; kt < KT; ++kt) {
        if (kt < KT - 1) VMCNT6(); else VMCNT0();   // tile kt's 6 loads complete
        BARRIER();
        const bool pre = (kt + 2 < KT);
        const int preBuf = (b0 + 2 >= 3) ? b0 - 1 : b0 + 2;
        PHASE(b0, 0, preBuf, kt + 2, pre);
        PHASE(b0, 1, preBuf, kt + 2, pre);
        b0 = (b0 + 1 == 3) ? 0 : b0 + 1;
    }

    // epilogue
    const int col = ncol0 + (wc << 4) + r;
    const bool live = (col < nint);
    const float nwv = live ? normw[col] : 0.f;
    #pragma unroll
    for (int m = 0; m < 8; ++m) {
        #pragma unroll
        for (int j = 0; j < 4; ++j) {
            int grow = mrow0 + (wr << 7) + (m << 4) + (q << 2) + j;
            float v = 0.f, ssq = 0.f;
            if (live) {
                float g = acc_g[m][j];
                float sg = g / (1.f + expf(-g));
                v = sg * acc_u[m][j];
                ssq = v * v;
                v *= nwv;
            }
            hid16[(size_t)grow * MAXF + col] = (f16)v;
            ssq += __shfl_xor(ssq, 1);
            ssq += __shfl_xor(ssq, 2);
            ssq += __shfl_xor(ssq, 4);
            ssq += __shfl_xor(ssq, 8);
            if (r == 0) atomicAdd(&sumsq[grow], ssq);
        }
    }
}

// =======================================================================================
// down GEMM: BM=256, BN=128, BK=64, 8 waves (2M x 4N), 3-buffer counted-vmcnt
// LDS per buffer (48KB): A slots 0..31 (as above); B slots 32..47: k8=(s-32)>>1, colblk=(s-32)&1
// =======================================================================================
__global__ __launch_bounds__(512, 2) void k_gemm_down(const f16* __restrict__ hid16,
                                                      const f16* __restrict__ dw16,
                                                      float* __restrict__ out,
                                                      const float* __restrict__ sumsq,
                                                      const float* __restrict__ nfp,
                                                      const int* __restrict__ np) {
    __shared__ __align__(16) f16 S[3 * 24576];   // 144 KB
    const int nint = *np;
    const float nf = *nfp;
    const int kT = (nint + 63) >> 6;
    const int ncol0 = blockIdx.y << 7;           // e-dim: 16 blocks
    const int mrow0 = blockIdx.x << 8;           // 32 blocks
    const int wave = threadIdx.x >> 6, lane = threadIdx.x & 63;
    const int wr = wave >> 2, wc = wave & 3;     // per-wave out: 128 rows x 32 cols
    const int q = lane >> 4, r = lane & 15;

    float4_t acc[8][2];
    const float4_t z = {0.f, 0.f, 0.f, 0.f};
    #pragma unroll
    for (int m = 0; m < 8; ++m) { acc[m][0] = z; acc[m][1] = z; }

    auto STAGE3 = [&](int buf, int kt, int half) {
        const int k0 = kt << 6;
        #pragma unroll
        for (int u = 0; u < 3; ++u) {
            const int s = wave * 6 + half * 3 + u;
            f16* dst = &S[buf * 24576 + (s << 9)];
            const f16* src;
            if (s < 32) { int k8 = s >> 2, rb = s & 3;
                          src = hid16 + (size_t)(mrow0 + (rb << 6) + lane) * MAXF + k0 + (k8 << 3); }
            else        { int j = s - 32, k8 = j >> 1, cb = j & 1;
                          src = dw16  + (size_t)(ncol0 + (cb << 6) + lane) * MAXF + k0 + (k8 << 3); }
            gload16(src, dst);
        }
    };

    auto PHASE = [&](int buf, int ks, int preBuf, int preKt, bool pre) {
        const f16* Sc = &S[buf * 24576];
        const int kq = (ks << 2) + q;
        half8_t af[8], bf[2];
        #pragma unroll
        for (int m = 0; m < 8; ++m) {
            int row = (wr << 7) + (m << 4) + r;
            af[m] = *(const half8_t*)(Sc + (((kq << 2) + (row >> 6)) << 9) + ((row & 63) << 3));
        }
        #pragma unroll
        for (int nn = 0; nn < 2; ++nn) {
            int c = (wc << 5) + (nn << 4) + r;
            bf[nn] = *(const half8_t*)(Sc + ((32 + (kq << 1) + (c >> 6)) << 9) + ((c & 63) << 3));
        }
        if (pre) STAGE3(preBuf, preKt, ks);
        BARRIER();
        LGKM0();
        __builtin_amdgcn_s_setprio(1);
        #pragma unroll
        for (int m = 0; m < 8; ++m) {
            acc[m][0] = __builtin_amdgcn_mfma_f32_16x16x32_f16(af[m], bf[0], acc[m][0], 0, 0, 0);
            acc[m][1] = __builtin_amdgcn_mfma_f32_16x16x32_f16(af[m], bf[1], acc[m][1], 0, 0, 0);
        }
        __builtin_amdgcn_s_setprio(0);
        BARRIER();
    };

    STAGE3(0, 0, 0); STAGE3(0, 0, 1);
    if (kT > 1) { STAGE3(1, 1, 0); STAGE3(1, 1, 1); }

    int b0 = 0;
    for (int kt = 0; kt < kT; ++kt) {
        if (kt < kT - 1) VMCNT6(); else VMCNT0();
        BARRIER();
        const bool pre = (kt + 2 < kT);
        const int preBuf = (b0 + 2 >= 3) ? b0 - 1 : b0 + 2;
        PHASE(b0, 0, preBuf, kt + 2, pre);
        PHASE(b0, 1, preBuf, kt + 2, pre);
        b0 = (b0 + 1 == 3) ? 0 : b0 + 1;
    }

    #pragma unroll
    for (int m = 0; m < 8; ++m) {
        #pragma unroll
        for (int j = 0; j < 4; ++j) {
            int grow = mrow0 + (wr << 7) + (m << 4) + (q << 2) + j;
            float rms = sqrtf(sumsq[grow] / nf + 1e-6f);
            rms = fminf(fmaxf(rms, 1e-6f), 1e6f);
            float inv = 1.f / rms;
            #pragma unroll
            for (int nn = 0; nn < 2; ++nn) {
                int c = ncol0 + (wc << 5) + (nn << 4) + r;
                out[(size_t)grow * EMB + c] = acc[m][nn][j] * inv;
            }
        }
    }
}

// ---------------- launch ----------------
extern "C" void kernel_launch(void* const* d_in, const int* in_sizes, int n_in,
                              void* d_out, int out_size, void* d_ws, size_t ws_size,
                              hipStream_t stream) {
    (void)in_sizes; (void)n_in; (void)out_size; (void)ws_size;
    const float* x  = (const float*)d_in[0];
    const float* w1 = (const float*)d_in[1];
    const float* w2 = (const float*)d_in[2];
    const float* gw = (const float*)d_in[3];
    const float* uw = (const float*)d_in[4];
    const float* dw = (const float*)d_in[5];
    const float* nw = (const float*)d_in[6];
    float* out = (float*)d_out;
    char* ws = (char*)d_ws;

    f16* x16   = (f16*)(ws + OFF_X16);
    f16* gw16  = (f16*)(ws + OFF_GW16);
    f16* uw16  = (f16*)(ws + OFF_UW16);
    f16* hid16 = (f16*)(ws + OFF_HID);
    f16* dw16  = (f16*)(ws + OFF_DW16);
    float* sumsq  = (float*)(ws + OFF_SMALL);
    float* meanx  = (float*)(ws + OFF_SMALL + 32768);
    float* hbuf   = (float*)(ws + OFF_SMALL + 65536);
    float* scal_f = (float*)(ws + OFF_SMALL + 73728);
    int*   scal_i = (int*)(ws + OFF_SMALL + 73728 + 4);

    // zero accumulators (sumsq + meanx contiguous: 16384 floats)
    k_zero<<<64, 256, 0, stream>>>(sumsq, 16384);

    // fp32 -> fp16 conversions
    k_cast_f2h<<<1024, 256, 0, stream>>>(x,  x16,  (MTOT * EMB) / 8);
    k_cast_f2h<<<1024, 256, 0, stream>>>(gw, gw16, (MAXF * EMB) / 8);
    k_cast_f2h<<<1024, 256, 0, stream>>>(uw, uw16, (MAXF * EMB) / 8);

    // dim predictor (fp32, exact-path)
    k_meanpart<<<256, 256, 0, stream>>>(x, meanx);
    k_pred1<<<512, 256, 0, stream>>>(meanx, w1, hbuf);
    k_pred2<<<1, 64, 0, stream>>>(hbuf, w2, scal_f, scal_i);

    // fused gate+up SwiGLU  (BM=256 x BN=64; mrow fast-varying)
    k_gemm_fused<<<dim3(32, 144), 512, 0, stream>>>(x16, gw16, uw16, hid16, nw, sumsq, scal_i);

    // down projection (BM=256 x BN=128)
    k_cast_f2h<<<1024, 256, 0, stream>>>(dw, dw16, (EMB * MAXF) / 8);   // overlays dead x16/gw16
    k_gemm_down<<<dim3(32, 16), 512, 0, stream>>>(hid16, dw16, out, sumsq, scal_f, scal_i);
}

// Round 6
// 1128.690 us; speedup vs baseline: 1.5931x; 1.4186x over previous
//
#include <hip/hip_runtime.h>
#include <hip/hip_fp16.h>
#include <cstdint>
#include <cstddef>

#define EMB    2048
#define MAXF   9216
#define NBATCH 4
#define NSEQ   2048
#define MTOT   (NBATCH*NSEQ)   // 8192

typedef _Float16 f16;
typedef _Float16 half8_t  __attribute__((ext_vector_type(8)));
typedef float    float4_t __attribute__((ext_vector_type(4)));

#define BARRIER()  __builtin_amdgcn_s_barrier()
#define VMCNT8()   asm volatile("s_waitcnt vmcnt(8)" ::: "memory")
#define VMCNT4()   asm volatile("s_waitcnt vmcnt(4)" ::: "memory")
#define VMCNT0()   asm volatile("s_waitcnt vmcnt(0)" ::: "memory")
#define LGKM0()    do { asm volatile("s_waitcnt lgkmcnt(0)" ::: "memory"); \
                        __builtin_amdgcn_sched_barrier(0); } while (0)

// ---------------- workspace layout (bytes) ----------------
static const size_t OFF_X16   = 0;
static const size_t OFF_GW16  = 33554432;
static const size_t OFF_UW16  = 71303168;
static const size_t OFF_HID   = 109051904;
static const size_t OFF_DW16  = 0;           // overlays x16/gw16 after fused pass
static const size_t OFF_SMALL = 260046848;

// ---------------- small kernels ----------------
__global__ void k_zero(float* __restrict__ p, int n) {
    int i = blockIdx.x * blockDim.x + threadIdx.x;
    if (i < n) p[i] = 0.f;
}

__global__ void k_cast_f2h(const float* __restrict__ s, f16* __restrict__ d, int n8) {
    int i   = blockIdx.x * blockDim.x + threadIdx.x;
    int str = gridDim.x * blockDim.x;
    for (; i < n8; i += str) {
        const float4* p = (const float4*)(s + (size_t)i * 8);
        float4 a = p[0], b = p[1];
        half8_t h;
        h[0] = (f16)a.x; h[1] = (f16)a.y; h[2] = (f16)a.z; h[3] = (f16)a.w;
        h[4] = (f16)b.x; h[5] = (f16)b.y; h[6] = (f16)b.z; h[7] = (f16)b.w;
        *(half8_t*)(d + (size_t)i * 8) = h;
    }
}

// cast only rows < ceil(n/128)*128 (gate/up weights beyond n are never staged)
__global__ void k_cast_f2h_n(const float* __restrict__ s, f16* __restrict__ d,
                             const int* __restrict__ np) {
    int lim = ((*np + 127) & ~127) << 8;   // rows * (EMB/8)
    int i   = blockIdx.x * blockDim.x + threadIdx.x;
    int str = gridDim.x * blockDim.x;
    for (; i < lim; i += str) {
        const float4* p = (const float4*)(s + (size_t)i * 8);
        float4 a = p[0], b = p[1];
        half8_t h;
        h[0] = (f16)a.x; h[1] = (f16)a.y; h[2] = (f16)a.z; h[3] = (f16)a.w;
        h[4] = (f16)b.x; h[5] = (f16)b.y; h[6] = (f16)b.z; h[7] = (f16)b.w;
        *(half8_t*)(d + (size_t)i * 8) = h;
    }
}

__global__ void k_meanpart(const float* __restrict__ x, float* __restrict__ meanx) {
    int bid = blockIdx.x;            // 256 blocks: b(4) x sc(8) x ec(8)
    int b  = bid >> 6;
    int sc = (bid >> 3) & 7;
    int ec = bid & 7;
    int e  = (ec << 8) + threadIdx.x;
    const float* p = x + (size_t)b * NSEQ * EMB + (size_t)(sc * 256) * EMB + e;
    float acc = 0.f;
    #pragma unroll 4
    for (int s2 = 0; s2 < 256; ++s2) acc += p[(size_t)s2 * EMB];
    atomicAdd(&meanx[b * EMB + e], acc);
}

__global__ void k_pred1(const float* __restrict__ meanx, const float* __restrict__ w1,
                        float* __restrict__ hbuf) {
    int g    = blockIdx.x * 4 + (threadIdx.x >> 6);  // 2048 waves
    int lane = threadIdx.x & 63;
    int b = g >> 9, j = g & 511;
    const float* mp = meanx + b * EMB;
    const float* wp = w1 + (size_t)j * EMB;
    float acc = 0.f;
    #pragma unroll 8
    for (int t = 0; t < 32; ++t) { int e = (t << 6) + lane; acc += mp[e] * wp[e]; }
    for (int o = 1; o < 64; o <<= 1) acc += __shfl_xor(acc, o);
    if (lane == 0) {
        float v = acc * (1.0f / (float)NSEQ);
        hbuf[(b << 9) + j] = v / (1.f + expf(-v));
    }
}

__global__ void k_pred2(const float* __restrict__ hbuf, const float* __restrict__ w2,
                        float* __restrict__ scal_f, int* __restrict__ scal_i) {
    int lane = threadIdx.x & 63;
    float rs = 0.f;
    for (int b = 0; b < 4; ++b) {
        float a = 0.f;
        #pragma unroll
        for (int t = 0; t < 8; ++t) { int e = (t << 6) + lane; a += hbuf[(b << 9) + e] * w2[e]; }
        for (int o = 1; o < 64; o <<= 1) a += __shfl_xor(a, o);
        float r = 1.f / (1.f + expf(-a));
        float ratio = 1.0f + (r - 0.5f);            // *2*ADAPT with ADAPT=0.5
        ratio = fminf(fmaxf(ratio, 0.5f), 1.5f);
        rs += ratio;
    }
    float n = floorf(6144.0f * (rs * 0.25f));
    n = fminf(fmaxf(n, 1.0f), 9216.0f);
    if (threadIdx.x == 0) { scal_f[0] = n; scal_i[0] = (int)n; }
}

// ---------------- staging helper ----------------
__device__ __forceinline__ void gload16(const f16* g, f16* l) {
    __builtin_amdgcn_global_load_lds((const __attribute__((address_space(1))) void*)g,
                                     (__attribute__((address_space(3))) void*)l, 16, 0, 0);
}

// =======================================================================================
// fused gate+up GEMM: BM=256, BN=128, BK=32, 8 waves (2M x 4N)
// 4 rotating 32KB buffers (128KB LDS), stage-ahead=3, vmcnt(8) steady, 1 barrier/K-tile.
// Buffer layout: 32 slots of 1KB (64 lanes x 16B):
//   A  slots  0..15 : k8 = s>>2 (8-half group), rb = s&3 (64 rows)   [256r x 32k]
//   Bg slots 16..23 : k8 = (s-16)>>1, cb = (s-16)&1                  [128c x 32k]
//   Bu slots 24..31 : k8 = (s-24)>>1, cb = (s-24)&1
// Per-wave per tile: 32 MFMA (8m x 2n x 2mat), 12 ds_read_b128, 4 gload_lds.
// =======================================================================================
__global__ __launch_bounds__(512, 2) void k_gemm_fused(const f16* __restrict__ x16,
                                                       const f16* __restrict__ gw16,
                                                       const f16* __restrict__ uw16,
                                                       f16* __restrict__ hid16,
                                                       const float* __restrict__ normw,
                                                       float* __restrict__ sumsq,
                                                       const int* __restrict__ np) {
    __shared__ __align__(16) f16 S[4 * 16384];   // 128 KB
    const int nint = *np;
    const int ncol0 = blockIdx.y << 7;
    if (ncol0 >= nint) return;
    const int mrow0 = blockIdx.x << 8;
    const int wave = threadIdx.x >> 6, lane = threadIdx.x & 63;
    const int wr = wave >> 2, wc = wave & 3;
    const int q = lane >> 4, r = lane & 15;
    const int KT = EMB / 32;                      // 64

    float4_t acc_g[8][2], acc_u[8][2];
    const float4_t z = {0.f, 0.f, 0.f, 0.f};
    #pragma unroll
    for (int m = 0; m < 8; ++m)
        #pragma unroll
        for (int nn = 0; nn < 2; ++nn) { acc_g[m][nn] = z; acc_u[m][nn] = z; }

    auto STAGE4 = [&](int buf, int kt) {
        const int k0 = kt << 5;
        #pragma unroll
        for (int u = 0; u < 4; ++u) {
            const int s = (wave << 2) + u;
            f16* dst = &S[buf * 16384 + (s << 9)];
            const f16* src;
            if (s < 16)      { int k8 = s >> 2, rb = s & 3;
                               src = x16  + (size_t)(mrow0 + (rb << 6) + lane) * EMB + k0 + (k8 << 3); }
            else if (s < 24) { int s2 = s - 16; int k8 = s2 >> 1, cb = s2 & 1;
                               src = gw16 + (size_t)(ncol0 + (cb << 6) + lane) * EMB + k0 + (k8 << 3); }
            else             { int s2 = s - 24; int k8 = s2 >> 1, cb = s2 & 1;
                               src = uw16 + (size_t)(ncol0 + (cb << 6) + lane) * EMB + k0 + (k8 << 3); }
            gload16(src, dst);
        }
    };

    // prologue: tiles 0,1,2 in flight (12 loads/thread)
    STAGE4(0, 0); STAGE4(1, 1); STAGE4(2, 2);

    for (int kt = 0; kt < KT; ++kt) {
        const int rem = KT - 1 - kt;
        if (rem >= 2) VMCNT8(); else if (rem == 1) VMCNT4(); else VMCNT0();
        BARRIER();                                   // tile kt fully in LDS for all waves
        const f16* Sc = &S[(kt & 3) * 16384];
        half8_t af[8], bg[2], bu[2];
        #pragma unroll
        for (int m = 0; m < 8; ++m) {
            int R = (wr << 7) + (m << 4) + r;
            af[m] = *(const half8_t*)(Sc + (((q << 2) | (R >> 6)) << 9) + ((R & 63) << 3));
        }
        #pragma unroll
        for (int nn = 0; nn < 2; ++nn) {
            int C = (wc << 5) + (nn << 4) + r;
            bg[nn] = *(const half8_t*)(Sc + ((16 + ((q << 1) | (C >> 6))) << 9) + ((C & 63) << 3));
            bu[nn] = *(const half8_t*)(Sc + ((24 + ((q << 1) | (C >> 6))) << 9) + ((C & 63) << 3));
        }
        if (kt + 3 < KT) STAGE4((kt + 3) & 3, kt + 3);   // overlaps ds_read latency
        LGKM0();
        __builtin_amdgcn_s_setprio(1);
        #pragma unroll
        for (int m = 0; m < 8; ++m) {
            acc_g[m][0] = __builtin_amdgcn_mfma_f32_16x16x32_f16(af[m], bg[0], acc_g[m][0], 0, 0, 0);
            acc_g[m][1] = __builtin_amdgcn_mfma_f32_16x16x32_f16(af[m], bg[1], acc_g[m][1], 0, 0, 0);
            acc_u[m][0] = __builtin_amdgcn_mfma_f32_16x16x32_f16(af[m], bu[0], acc_u[m][0], 0, 0, 0);
            acc_u[m][1] = __builtin_amdgcn_mfma_f32_16x16x32_f16(af[m], bu[1], acc_u[m][1], 0, 0, 0);
        }
        __builtin_amdgcn_s_setprio(0);
        // no trailing barrier: buffer reuse protected by leading barrier + own lgkm
    }

    // epilogue: h = silu(g)*u (masked), rowwise ssq, store h*norm_w as fp16
    #pragma unroll
    for (int nn = 0; nn < 2; ++nn) {
        const int col = ncol0 + (wc << 5) + (nn << 4) + r;
        const bool live = (col < nint);
        const float nwv = live ? normw[col] : 0.f;
        #pragma unroll
        for (int m = 0; m < 8; ++m) {
            #pragma unroll
            for (int j = 0; j < 4; ++j) {
                int grow = mrow0 + (wr << 7) + (m << 4) + (q << 2) + j;
                float v = 0.f, ssq = 0.f;
                if (live) {
                    float g = acc_g[m][nn][j];
                    float sg = g / (1.f + expf(-g));
                    v = sg * acc_u[m][nn][j];
                    ssq = v * v;
                    v *= nwv;
                }
                hid16[(size_t)grow * MAXF + col] = (f16)v;
                ssq += __shfl_xor(ssq, 1);
                ssq += __shfl_xor(ssq, 2);
                ssq += __shfl_xor(ssq, 4);
                ssq += __shfl_xor(ssq, 8);
                if (r == 0) atomicAdd(&sumsq[grow], ssq);
            }
        }
    }
}

// =======================================================================================
// down GEMM: BM=256, BN=256, BK=32, 8 waves (2M x 4N), same 4-buffer skeleton
// Buffer: A slots 0..15 (as fused); B slots 16..31: k8=(s-16)>>2, cb=(s-16)&3 [256c x 32k]
// Per-wave per tile: 32 MFMA (8m x 4n), 12 ds_read_b128, 4 gload_lds.
// Grid: 32 x 8 = 256 blocks = 1/CU.
// =======================================================================================
__global__ __launch_bounds__(512, 2) void k_gemm_down(const f16* __restrict__ hid16,
                                                      const f16* __restrict__ dw16,
                                                      float* __restrict__ out,
                                                      const float* __restrict__ sumsq,
                                                      const float* __restrict__ nfp,
                                                      const int* __restrict__ np) {
    __shared__ __align__(16) f16 S[4 * 16384];   // 128 KB
    const int nint = *np;
    const float nf = *nfp;
    const int kT = (nint + 31) >> 5;             // >= 96
    const int ncol0 = blockIdx.y << 8;
    const int mrow0 = blockIdx.x << 8;
    const int wave = threadIdx.x >> 6, lane = threadIdx.x & 63;
    const int wr = wave >> 2, wc = wave & 3;
    const int q = lane >> 4, r = lane & 15;

    float4_t acc[8][4];
    const float4_t z = {0.f, 0.f, 0.f, 0.f};
    #pragma unroll
    for (int m = 0; m < 8; ++m)
        #pragma unroll
        for (int nn = 0; nn < 4; ++nn) acc[m][nn] = z;

    auto STAGE4 = [&](int buf, int kt) {
        const int k0 = kt << 5;
        #pragma unroll
        for (int u = 0; u < 4; ++u) {
            const int s = (wave << 2) + u;
            f16* dst = &S[buf * 16384 + (s << 9)];
            const f16* src;
            if (s < 16) { int k8 = s >> 2, rb = s & 3;
                          src = hid16 + (size_t)(mrow0 + (rb << 6) + lane) * MAXF + k0 + (k8 << 3); }
            else        { int s2 = s - 16; int k8 = s2 >> 2, cb = s2 & 3;
                          src = dw16  + (size_t)(ncol0 + (cb << 6) + lane) * MAXF + k0 + (k8 << 3); }
            gload16(src, dst);
        }
    };

    STAGE4(0, 0); STAGE4(1, 1); STAGE4(2, 2);

    for (int kt = 0; kt < kT; ++kt) {
        const int rem = kT - 1 - kt;
        if (rem >= 2) VMCNT8(); else if (rem == 1) VMCNT4(); else VMCNT0();
        BARRIER();
        const f16* Sc = &S[(kt & 3) * 16384];
        half8_t af[8], bf[4];
        #pragma unroll
        for (int m = 0; m < 8; ++m) {
            int R = (wr << 7) + (m << 4) + r;
            af[m] = *(const half8_t*)(Sc + (((q << 2) | (R >> 6)) << 9) + ((R & 63) << 3));
        }
        #pragma unroll
        for (int nn = 0; nn < 4; ++nn) {
            int C = (wc << 6) + (nn << 4) + r;
            bf[nn] = *(const half8_t*)(Sc + ((16 + ((q << 2) | (C >> 6))) << 9) + ((C & 63) << 3));
        }
        if (kt + 3 < kT) STAGE4((kt + 3) & 3, kt + 3);
        LGKM0();
        __builtin_amdgcn_s_setprio(1);
        #pragma unroll
        for (int m = 0; m < 8; ++m)
            #pragma unroll
            for (int nn = 0; nn < 4; ++nn)
                acc[m][nn] = __builtin_amdgcn_mfma_f32_16x16x32_f16(af[m], bf[nn], acc[m][nn], 0, 0, 0);
        __builtin_amdgcn_s_setprio(0);
    }

    #pragma unroll
    for (int m = 0; m < 8; ++m) {
        #pragma unroll
        for (int j = 0; j < 4; ++j) {
            int grow = mrow0 + (wr << 7) + (m << 4) + (q << 2) + j;
            float rms = sqrtf(sumsq[grow] / nf + 1e-6f);
            rms = fminf(fmaxf(rms, 1e-6f), 1e6f);
            float inv = 1.f / rms;
            #pragma unroll
            for (int nn = 0; nn < 4; ++nn) {
                int c = ncol0 + (wc << 6) + (nn << 4) + r;
                out[(size_t)grow * EMB + c] = acc[m][nn][j] * inv;
            }
        }
    }
}

// ---------------- launch ----------------
extern "C" void kernel_launch(void* const* d_in, const int* in_sizes, int n_in,
                              void* d_out, int out_size, void* d_ws, size_t ws_size,
                              hipStream_t stream) {
    (void)in_sizes; (void)n_in; (void)out_size; (void)ws_size;
    const float* x  = (const float*)d_in[0];
    const float* w1 = (const float*)d_in[1];
    const float* w2 = (const float*)d_in[2];
    const float* gw = (const float*)d_in[3];
    const float* uw = (const float*)d_in[4];
    const float* dw = (const float*)d_in[5];
    const float* nw = (const float*)d_in[6];
    float* out = (float*)d_out;
    char* ws = (char*)d_ws;

    f16* x16   = (f16*)(ws + OFF_X16);
    f16* gw16  = (f16*)(ws + OFF_GW16);
    f16* uw16  = (f16*)(ws + OFF_UW16);
    f16* hid16 = (f16*)(ws + OFF_HID);
    f16* dw16  = (f16*)(ws + OFF_DW16);
    float* sumsq  = (float*)(ws + OFF_SMALL);
    float* meanx  = (float*)(ws + OFF_SMALL + 32768);
    float* hbuf   = (float*)(ws + OFF_SMALL + 65536);
    float* scal_f = (float*)(ws + OFF_SMALL + 73728);
    int*   scal_i = (int*)(ws + OFF_SMALL + 73728 + 4);

    // zero accumulators (sumsq + meanx contiguous: 16384 floats)
    k_zero<<<64, 256, 0, stream>>>(sumsq, 16384);

    // dim predictor first (its result bounds the weight casts)
    k_meanpart<<<256, 256, 0, stream>>>(x, meanx);
    k_pred1<<<512, 256, 0, stream>>>(meanx, w1, hbuf);
    k_pred2<<<1, 64, 0, stream>>>(hbuf, w2, scal_f, scal_i);

    // fp32 -> fp16 conversions (gate/up bounded by ceil(n/128)*128 rows)
    k_cast_f2h<<<1024, 256, 0, stream>>>(x, x16, (MTOT * EMB) / 8);
    k_cast_f2h_n<<<1024, 256, 0, stream>>>(gw, gw16, scal_i);
    k_cast_f2h_n<<<1024, 256, 0, stream>>>(uw, uw16, scal_i);

    // fused gate+up SwiGLU  (BM=256 x BN=128)
    k_gemm_fused<<<dim3(32, 72), 512, 0, stream>>>(x16, gw16, uw16, hid16, nw, sumsq, scal_i);

    // down projection (BM=256 x BN=256, 256 blocks = 1/CU)
    k_cast_f2h<<<1024, 256, 0, stream>>>(dw, dw16, (EMB * MAXF) / 8);   // overlays dead x16/gw16
    k_gemm_down<<<dim3(32, 8), 512, 0, stream>>>(hid16, dw16, out, sumsq, scal_f, scal_i);
}